// Round 1
// baseline (1395.767 us; speedup 1.0000x reference)
//
#include <hip/hip_runtime.h>
#include <stdint.h>

#define CDIM   256
#define NPIX   65536
#define NBATCH 8
#define SLABS  64                          // column slabs per batch
#define SCOLS  1024                        // columns per slab (256 threads * 4)
#define NBLOCKS (NBATCH * SLABS)           // 512
#define KTHRESH 0.01

// workspace layout (float indices) -- unchanged from previous version
#define WS_DELTA 0        // 256 floats: normalize(c1)-normalize(c0)
#define WS_CENT  256      // 512 floats: current raw centers [K][C]
#define WS_T     768      // 2048 floats: per-batch totals  T[b][c]
#define WS_S1    2816     // 2048 floats: per-batch label-1 sums S1[b][c]
#define WS_CNT   4864     // 8 uints: per-batch label-1 counts
#define WS_DONE  4872     // 1 int: convergence flag

// output layout (floats): centers[2*256] | labels[8*65536] | onehot[8*65536*2] | cur_dist
#define OUT_LABELS 512
#define OUT_ONEHOT (512 + NBATCH * NPIX)
#define OUT_CDIST  (512 + NBATCH * NPIX + 2 * NBATCH * NPIX)

__device__ __forceinline__ double block_reduce(double v, double* sh) {
  const int t = threadIdx.x;
  #pragma unroll
  for (int off = 32; off > 0; off >>= 1) v += __shfl_down(v, off, 64);
  __syncthreads();
  if ((t & 63) == 0) sh[t >> 6] = v;
  __syncthreads();
  return sh[0] + sh[1] + sh[2] + sh[3];
}

__device__ __forceinline__ void block_reduce4(double v[4], double* sh) {
  const int t = threadIdx.x;
  #pragma unroll
  for (int off = 32; off > 0; off >>= 1) {
    v[0] += __shfl_down(v[0], off, 64);
    v[1] += __shfl_down(v[1], off, 64);
    v[2] += __shfl_down(v[2], off, 64);
    v[3] += __shfl_down(v[3], off, 64);
  }
  __syncthreads();
  if ((t & 63) == 0) {
    const int w = t >> 6;
    sh[w] = v[0]; sh[4 + w] = v[1]; sh[8 + w] = v[2]; sh[12 + w] = v[3];
  }
  __syncthreads();
  #pragma unroll
  for (int k = 0; k < 4; ++k) v[k] = sh[4 * k] + sh[4 * k + 1] + sh[4 * k + 2] + sh[4 * k + 3];
}

__global__ __launch_bounds__(256) void init_kernel(const float* __restrict__ cinit,
                                                   float* __restrict__ ws) {
  __shared__ double sh[16];
  const int t = threadIdx.x;
  for (int i = t; i < NBATCH * CDIM; i += 256) { ws[WS_T + i] = 0.f; ws[WS_S1 + i] = 0.f; }
  if (t < NBATCH) ((unsigned int*)(ws + WS_CNT))[t] = 0u;
  if (t == 0) ((int*)(ws + WS_DONE))[0] = 0;
  const float c0f = cinit[t], c1f = cinit[CDIM + t];
  ws[WS_CENT + t] = c0f;
  ws[WS_CENT + CDIM + t] = c1f;
  const double c0 = (double)c0f, c1 = (double)c1f;
  double n0 = sqrt(block_reduce(c0 * c0, sh));
  double n1 = sqrt(block_reduce(c1 * c1, sh));
  n0 = fmax(n0, 1e-12); n1 = fmax(n1, 1e-12);
  ws[WS_DELTA + t] = (float)(c1 / n1) - (float)(c0 / n0);
}

// Two coalesced sweeps over a 1024-column slab, no LDS staging:
//   phase A: float4 streaming loads (4 KB contiguous per block per channel),
//            4 independent fp64 dot chains in registers -> labels in registers.
//   phase B: re-read same addresses (reversed c for L3 tail reuse), masked
//            per-channel sums via wave shuffle-reduce -> per-wave LDS slot ->
//            one fp32 atomic per (b,c) per block.
__global__ __launch_bounds__(256) void pass_kernel(const float* __restrict__ F,
                                                   float* __restrict__ ws,
                                                   float* __restrict__ out,
                                                   int iter) {
  if (iter > 0 && ((const volatile int*)(ws + WS_DONE))[0] != 0) return;

  __shared__ double deltaD[CDIM];
  __shared__ float s1p[CDIM * 4];
  __shared__ float tp[CDIM * 4];
  __shared__ unsigned cntS;

  const int t = threadIdx.x;
  const int w = t >> 6;                       // wave 0..3
  const int l = t & 63;                       // lane
  const int b = blockIdx.x >> 6;              // batch
  const int n0 = (blockIdx.x & 63) * SCOLS;   // first column of this slab

  if (t < CDIM) deltaD[t] = (double)ws[WS_DELTA + t];
  if (t == 0) cntS = 0u;
  __syncthreads();

  const float4* __restrict__ Fv =
      (const float4*)(F + (size_t)b * CDIM * NPIX + n0);
  const int rstride = NPIX / 4;               // row stride in float4 units

  // ---- phase A: fp64 dots for this thread's 4 columns over all channels ----
  double d0 = 0.0, d1 = 0.0, d2 = 0.0, d3 = 0.0;
  #pragma unroll 16
  for (int c = 0; c < CDIM; ++c) {
    const float4 v = Fv[(size_t)c * rstride + t];
    const double dc = deltaD[c];
    d0 = fma(dc, (double)v.x, d0);
    d1 = fma(dc, (double)v.y, d1);
    d2 = fma(dc, (double)v.z, d2);
    d3 = fma(dc, (double)v.w, d3);
  }
  const float m0 = d0 > 0.0 ? 1.f : 0.f;
  const float m1 = d1 > 0.0 ? 1.f : 0.f;
  const float m2 = d2 > 0.0 ? 1.f : 0.f;
  const float m3 = d3 > 0.0 ? 1.f : 0.f;

  // labels + onehot (contiguous float4 stores)
  const int gi0 = b * NPIX + n0 + 4 * t;
  *(float4*)(out + OUT_LABELS + gi0) = make_float4(m0, m1, m2, m3);
  *(float4*)(out + OUT_ONEHOT + 2 * gi0)     = make_float4(1.f - m0, m0, 1.f - m1, m1);
  *(float4*)(out + OUT_ONEHOT + 2 * gi0 + 4) = make_float4(1.f - m2, m2, 1.f - m3, m3);

  // label-1 count (wave-uniform ballots, one LDS atomic per wave)
  const unsigned cw = (unsigned)(__popcll(__ballot(d0 > 0.0)) +
                                 __popcll(__ballot(d1 > 0.0)) +
                                 __popcll(__ballot(d2 > 0.0)) +
                                 __popcll(__ballot(d3 > 0.0)));
  if (l == 0) atomicAdd(&cntS, cw);

  // ---- phase B: masked per-channel sums (reversed c: newest lines first) ----
  const bool first = (iter == 0);
  #pragma unroll 8
  for (int c = CDIM - 1; c >= 0; --c) {
    const float4 v = Fv[(size_t)c * rstride + t];
    float s1 = 0.f;
    s1 = fmaf(m0, v.x, s1);
    s1 = fmaf(m1, v.y, s1);
    s1 = fmaf(m2, v.z, s1);
    s1 = fmaf(m3, v.w, s1);
    #pragma unroll
    for (int off = 32; off > 0; off >>= 1) s1 += __shfl_down(s1, off, 64);
    if (l == 0) s1p[4 * c + w] = s1;
    if (first) {
      float tc = (v.x + v.y) + (v.z + v.w);
      #pragma unroll
      for (int off = 32; off > 0; off >>= 1) tc += __shfl_down(tc, off, 64);
      if (l == 0) tp[4 * c + w] = tc;
    }
  }
  __syncthreads();

  // epilogue: thread t owns channel t; one atomic per (b,c) per block
  {
    const float s = (s1p[4 * t] + s1p[4 * t + 1]) + (s1p[4 * t + 2] + s1p[4 * t + 3]);
    unsafeAtomicAdd(&ws[WS_S1 + b * CDIM + t], s);
    if (first) {
      const float tt = (tp[4 * t] + tp[4 * t + 1]) + (tp[4 * t + 2] + tp[4 * t + 3]);
      unsafeAtomicAdd(&ws[WS_T + b * CDIM + t], tt);
    }
  }
  if (t == 0) atomicAdd(&((unsigned int*)(ws + WS_CNT))[b], cntS);
}

__global__ __launch_bounds__(256) void finalize_kernel(float* __restrict__ ws,
                                                       float* __restrict__ out) {
  __shared__ double sh[16];
  const int t = threadIdx.x;
  if (((const volatile int*)(ws + WS_DONE))[0] != 0) return;  // frozen: keep prior outputs

  const double cold0 = (double)ws[WS_CENT + t];
  const double cold1 = (double)ws[WS_CENT + CDIM + t];
  const double normc0 = sqrt(block_reduce(cold0 * cold0, sh));
  const double normc1 = sqrt(block_reduce(cold1 * cold1, sh));

  double acc0 = 0.0, acc1 = 0.0, cdsum = 0.0;
  for (int b = 0; b < NBATCH; ++b) {
    const double s1v  = (double)ws[WS_S1 + b * CDIM + t];
    const double totv = (double)ws[WS_T  + b * CDIM + t];
    const double c1n  = (double)((unsigned int*)(ws + WS_CNT))[b];
    const double ci1  = s1v / (c1n + 1.0);
    const double ci0  = (totv - s1v) / ((double)NPIX - c1n + 1.0);
    acc0 += ci0; acc1 += ci1;
    double v[4] = {ci0 * cold0, ci0 * ci0, ci1 * cold1, ci1 * ci1};
    block_reduce4(v, sh);
    const double den0 = fmax(sqrt(v[1]) * normc0, 1e-8);
    const double den1 = fmax(sqrt(v[3]) * normc1, 1e-8);
    cdsum += 0.5 * (v[0] / den0 + v[2] / den1);
  }
  const double curdist = cdsum / (double)NBATCH;
  const float nc0f = (float)(acc0 / (double)NBATCH);
  const float nc1f = (float)(acc1 / (double)NBATCH);

  ws[WS_CENT + t] = nc0f;
  ws[WS_CENT + CDIM + t] = nc1f;
  out[t] = nc0f;
  out[CDIM + t] = nc1f;
  if (t == 0) out[OUT_CDIST] = (float)curdist;

  double m0 = sqrt(block_reduce((double)nc0f * (double)nc0f, sh));
  double m1 = sqrt(block_reduce((double)nc1f * (double)nc1f, sh));
  m0 = fmax(m0, 1e-12); m1 = fmax(m1, 1e-12);
  ws[WS_DELTA + t] = (float)((double)nc1f / m1) - (float)((double)nc0f / m0);

  __syncthreads();
  for (int i = t; i < NBATCH * CDIM; i += 256) ws[WS_S1 + i] = 0.f;
  if (t < NBATCH) ((unsigned int*)(ws + WS_CNT))[t] = 0u;
  if (t == 0) ((int*)(ws + WS_DONE))[0] = (curdist < KTHRESH) ? 1 : 0;
}

extern "C" void kernel_launch(void* const* d_in, const int* in_sizes, int n_in,
                              void* d_out, int out_size, void* d_ws, size_t ws_size,
                              hipStream_t stream) {
  const float* F     = (const float*)d_in[0];
  const float* cinit = (const float*)d_in[1];
  float* out = (float*)d_out;
  float* ws  = (float*)d_ws;

  init_kernel<<<1, 256, 0, stream>>>(cinit, ws);
  for (int iter = 0; iter < 3; ++iter) {
    pass_kernel<<<NBLOCKS, 256, 0, stream>>>(F, ws, out, iter);
    finalize_kernel<<<1, 256, 0, stream>>>(ws, out);
  }
}